// Round 9
// baseline (29.379 us; speedup 1.0000x reference)
//
#include <hip/hip_runtime.h>

#define S_DIM 64
#define B_DIM 256
#define D_DIM 1024
#define BS (B_DIM * S_DIM)        /* 16384 */
#define LP (B_DIM * (S_DIM - 1)) /* 16128 */
#define NBP 128                   /* blocks in pair_kernel */
#define PSTR 8                    /* partials per row (2 halves x 4 quarters) */

__device__ __forceinline__ float dot4(float4 a, float4 b) {
  return a.x * b.x + a.y * b.y + a.z * b.z + a.w * b.w;
}

// DPP row_ror add (pure VALU): after 4 steps every lane holds its 16-lane
// row's sum. No readlane finish -- we store 4 quarter-partials per wave.
template <int CTRL>
__device__ __forceinline__ float dpp_add(float v) {
  int r = __builtin_amdgcn_update_dpp(__float_as_int(v), __float_as_int(v),
                                      CTRL, 0xF, 0xF, false);
  return v + __int_as_float(r);
}

__device__ __forceinline__ float red16(float v) {
  v = dpp_add<0x128>(v);  // row_ror:8
  v = dpp_add<0x124>(v);  // row_ror:4
  v = dpp_add<0x122>(v);  // row_ror:2
  v = dpp_add<0x121>(v);  // row_ror:1
  return v;
}

// Full 64-lane reduce (tail kernels only).
__device__ __forceinline__ float red64_uni(float v) {
  v = red16(v);
  float r = __int_as_float(__builtin_amdgcn_readlane(__float_as_int(v), 0));
  r += __int_as_float(__builtin_amdgcn_readlane(__float_as_int(v), 16));
  r += __int_as_float(__builtin_amdgcn_readlane(__float_as_int(v), 32));
  r += __int_as_float(__builtin_amdgcn_readlane(__float_as_int(v), 48));
  return r;
}

// ---------------------------------------------------------------------------
// Kernel 1: per-row reductions. Fully autonomous waves (no LDS, no barrier):
// one wave per {batch, 2-row chunk, d-half}. MASK-GATED loads (invalid rows
// contribute nothing anywhere). Boundary prev-row read redundantly from
// global -- proven free (L3 hit, R7 null). Reduction truncated at 16-lane
// rows: 4 quarter-partials stored per half-row by lanes 0/16/32/48.
// ws layout (floats): nl2p[8BS] | nt2p[8BS] | ltp[8BS] | ajlp[8BS] | ajtp[8BS]
//                     | partial[6*NBP]
// Partial index: 8*rowid + h*4 + quarter. Unwritten entries are never read.
// ---------------------------------------------------------------------------
__global__ __launch_bounds__(256) void row_stats_kernel(
    const float* __restrict__ logits, const float* __restrict__ tgt,
    const unsigned char* __restrict__ mask, float* __restrict__ ws) {
  const int tid = threadIdx.x;
  const int lane = tid & 63;
  int bid = blockIdx.x;
  bid = (bid & 7) * 512 + (bid >> 3);      // XCD swizzle, bijective (4096%8==0)
  const int gw = (bid << 2) | (tid >> 6);  // 0..16383
  const int h  = gw & 1;                   // d-half
  const int s0 = ((gw >> 1) & 31) << 1;    // 0,2,...,62
  const int b  = gw >> 6;                  // batch

  float* nl2p = ws;
  float* nt2p = ws + 8 * BS;
  float* ltp  = ws + 16 * BS;
  float* ajlp = ws + 24 * BS;
  float* ajtp = ws + 32 * BS;

  // Mask layout detection (byte vs int32), wave-local broadcast reads.
  uchar4 det = reinterpret_cast<const uchar4*>(mask)[lane];
  const bool isbyte = __ballot((det.y | det.z | det.w) != 0) != 0ull;
  auto mvalid = [&](int s) -> bool {
    const int idx = b * S_DIM + s;
    return mask[isbyte ? idx : (idx << 2)] == 0;
  };
  const bool v0 = mvalid(s0);
  const bool v1 = mvalid(s0 + 1);
  const bool vp = (s0 > 0) && mvalid(s0 - 1);
  const bool needP  = v0 && vp;   // pair (s0-1, s0)
  const bool needP1 = v0 && v1;   // pair (s0, s0+1)

  const int fo = h * 128 + lane;  // float4 index within row (+64 for j=1)

  float4 R[4], N[4], P[4];  // rows s0, s0+1, s0-1; [0..1]=logits, [2..3]=tgt

  auto ldrow = [&](int s, float4* dst) {
    const float4* Lp = reinterpret_cast<const float4*>(
        logits + ((size_t)s * B_DIM + b) * D_DIM);
    const float4* Tp = reinterpret_cast<const float4*>(
        tgt + ((size_t)s * B_DIM + b) * D_DIM);
    dst[0] = Lp[fo];
    dst[1] = Lp[fo + 64];
    dst[2] = Tp[fo];
    dst[3] = Tp[fo + 64];
  };

  if (v0) ldrow(s0, R);
  if (v1) ldrow(s0 + 1, N);
  if (needP) ldrow(s0 - 1, P);

  float a0 = 0.f, a1 = 0.f, a2 = 0.f, a3 = 0.f, a4 = 0.f;
  float b0 = 0.f, b1 = 0.f, b2 = 0.f, b3 = 0.f, b4 = 0.f;
  if (v0) {
    a0 = dot4(R[0], R[0]) + dot4(R[1], R[1]);
    a1 = dot4(R[2], R[2]) + dot4(R[3], R[3]);
    a2 = dot4(R[0], R[2]) + dot4(R[1], R[3]);
  }
  if (needP) {
    a3 = dot4(R[0], P[0]) + dot4(R[1], P[1]);  // aj[s0-1] logits
    a4 = dot4(R[2], P[2]) + dot4(R[3], P[3]);  // aj[s0-1] tgt
  }
  if (v1) {
    b0 = dot4(N[0], N[0]) + dot4(N[1], N[1]);
    b1 = dot4(N[2], N[2]) + dot4(N[3], N[3]);
    b2 = dot4(N[0], N[2]) + dot4(N[1], N[3]);
  }
  if (needP1) {
    b3 = dot4(N[0], R[0]) + dot4(N[1], R[1]);  // aj[s0] logits
    b4 = dot4(N[2], R[2]) + dot4(N[3], R[3]);  // aj[s0] tgt
  }

  if (v0) { a0 = red16(a0); a1 = red16(a1); a2 = red16(a2); }
  if (needP) { a3 = red16(a3); a4 = red16(a4); }
  if (v1) { b0 = red16(b0); b1 = red16(b1); b2 = red16(b2); }
  if (needP1) { b3 = red16(b3); b4 = red16(b4); }

  if ((lane & 15) == 0) {  // lanes 0,16,32,48: quarter-partial leaders
    const int q = lane >> 4;
    const int i = b * S_DIM + s0;
    const int o = PSTR * i + h * 4 + q;
    if (v0) { nl2p[o] = a0; nt2p[o] = a1; ltp[o] = a2; }
    if (needP) { ajlp[o - PSTR] = a3; ajtp[o - PSTR] = a4; }
    if (v1) {
      nl2p[o + PSTR] = b0; nt2p[o + PSTR] = b1; ltp[o + PSTR] = b2;
    }
    if (needP1) { ajlp[o] = b3; ajtp[o] = b4; }
  }
}

// Sum the 8 partials of one row: two float4 loads.
__device__ __forceinline__ float ld8(const float* p, int i) {
  const float4* q4 = reinterpret_cast<const float4*>(p) + 2 * i;
  float4 x = q4[0], y = q4[1];
  return ((x.x + x.y) + (x.z + x.w)) + ((y.x + y.y) + (y.z + y.w));
}

// ---------------------------------------------------------------------------
// Kernel 2: mask-weighted row sums + pair delta/dd terms. 128 blocks x 128
// threads; ballot-built validity bitmaps make the next-valid-pair search a
// bit scan. Reads only entries whose validity gate passed in row_stats.
// ---------------------------------------------------------------------------
__global__ __launch_bounds__(128) void pair_kernel(
    const unsigned char* __restrict__ mask, float* __restrict__ ws) {
  const float* nl2p = ws;
  const float* nt2p = ws + 8 * BS;
  const float* ltp  = ws + 16 * BS;
  const float* ajlp = ws + 24 * BS;
  const float* ajtp = ws + 32 * BS;
  float* partial = ws + 40 * BS;

  __shared__ unsigned long long vb[16];
  __shared__ float psum[6][2];
  __shared__ int s_flag;

  const int tid = threadIdx.x;
  const int w = tid >> 6, lane = tid & 63;

  if (tid == 0) s_flag = 0;
  __syncthreads();
  int any = 0;
  for (int i = tid; i < 1024; i += 128)
    if ((i & 3) == 1 && mask[i]) any = 1;
  if (any) s_flag = 1;
  __syncthreads();
  const bool isbyte = (s_flag != 0);

  int B0 = (blockIdx.x * 128) / 63;
  if (B0 > B_DIM - 16) B0 = B_DIM - 16;

#pragma unroll
  for (int k = 0; k < 8; ++k) {
    const int q = k * 2 + w;
    const int g2 = (B0 + q) * 64 + lane;
    bool val = mask[isbyte ? g2 : (g2 << 2)] == 0;
    unsigned long long bal = __ballot(val);
    if (lane == 0) vb[q] = bal;
  }
  __syncthreads();

  const int g = blockIdx.x * 128 + tid;  // row id and pair id

  float nv = 0.f, mse = 0.f, coss = 0.f, dsum = 0.f, ddsum = 0.f, cntf = 0.f;

  // Row terms.
  if (mask[isbyte ? g : (g << 2)] == 0) {
    float A = ld8(nl2p, g), Q = ld8(nt2p, g), Cc = ld8(ltp, g);
    nv = 1.f;
    mse = A + Q - 2.f * Cc;
    coss = 1.f - Cc / (fmaxf(sqrtf(A), 1e-8f) * fmaxf(sqrtf(Q), 1e-8f));
  }

  // Pair terms.
  if (g < LP) {
    const int b = g / 63;
    const int s = g - b * 63;
    const unsigned long long pbb = vb[b - B0] & (vb[b - B0] >> 1);
    if ((pbb >> s) & 1ull) {
      const int i0 = b * S_DIM + s;
      float dl = ld8(ajlp, i0) / (fmaxf(sqrtf(ld8(nl2p, i0)), 1e-6f) *
                                  fmaxf(sqrtf(ld8(nl2p, i0 + 1)), 1e-6f));
      float dt = ld8(ajtp, i0) / (fmaxf(sqrtf(ld8(nt2p, i0)), 1e-6f) *
                                  fmaxf(sqrtf(ld8(nt2p, i0 + 1)), 1e-6f));
      float wv = dl - dt;
      dsum = wv * wv;
      cntf = 1.f;

      // Next valid pair: bit scan through the LDS window.
      int bq = b, sq = -1;
      bool found = false, fellback = false;
      unsigned long long cur = pbb & (~0ull << (s + 1));
      while (true) {
        if (cur) { sq = __builtin_ctzll(cur); found = true; break; }
        ++bq;
        if (bq >= B_DIM) break;
        if (bq - B0 < 16) {
          cur = vb[bq - B0] & (vb[bq - B0] >> 1);
        } else {
          fellback = true;
          break;
        }
      }
      if (fellback) {  // correctness fallback; ~never taken for random masks
        while (bq < B_DIM && !found) {
          for (int s2 = 0; s2 < 63; ++s2) {
            int r0 = bq * S_DIM + s2;
            bool q1 = mask[isbyte ? r0 : (r0 << 2)] == 0;
            bool q2 = mask[isbyte ? (r0 + 1) : ((r0 + 1) << 2)] == 0;
            if (q1 && q2) { sq = s2; found = true; break; }
          }
          if (!found) ++bq;
        }
      }
      if (found) {
        const int j0 = bq * S_DIM + sq;
        float dlq = ld8(ajlp, j0) / (fmaxf(sqrtf(ld8(nl2p, j0)), 1e-6f) *
                                     fmaxf(sqrtf(ld8(nl2p, j0 + 1)), 1e-6f));
        float dtq = ld8(ajtp, j0) / (fmaxf(sqrtf(ld8(nt2p, j0)), 1e-6f) *
                                     fmaxf(sqrtf(ld8(nt2p, j0 + 1)), 1e-6f));
        float ddl = (dlq - dl) / ((dl != 0.f) ? dl : 1e-6f);
        float ddt = (dtq - dt) / ((dt != 0.f) ? dt : 1e-6f);
        float u = ddl - ddt;
        ddsum = u * u;
      }
    }
  }

  float vals[6] = {nv, mse, coss, dsum, ddsum, cntf};
#pragma unroll
  for (int k2 = 0; k2 < 6; ++k2) {
    float v = red64_uni(vals[k2]);
    if (lane == 0) psum[k2][w] = v;
  }
  __syncthreads();
  if (tid == 0) {
#pragma unroll
    for (int k2 = 0; k2 < 6; ++k2)
      partial[k2 * NBP + blockIdx.x] = psum[k2][0] + psum[k2][1];
  }
}

// ---------------------------------------------------------------------------
// Kernel 3: combine 128 partials into the scalar loss.
// ---------------------------------------------------------------------------
__global__ __launch_bounds__(128) void final_combine_kernel(
    const float* __restrict__ ws, float* __restrict__ out) {
  const float* partial = ws + 40 * BS;
  __shared__ float sm[6][2];
  const int tid = threadIdx.x, w = tid >> 6, lane = tid & 63;
#pragma unroll
  for (int k = 0; k < 6; ++k) {
    float v = red64_uni(partial[k * NBP + tid]);
    if (lane == 0) sm[k][w] = v;
  }
  __syncthreads();
  if (tid == 0) {
    float nv   = sm[0][0] + sm[0][1];
    float mse  = sm[1][0] + sm[1][1];
    float coss = sm[2][0] + sm[2][1];
    float dsum = sm[3][0] + sm[3][1];
    float ddsm = sm[4][0] + sm[4][1];
    float cnt  = sm[5][0] + sm[5][1];
    out[0] = mse / (nv * (float)D_DIM) + coss / nv +
             dsum / fmaxf(cnt, 1.f) + (ddsm / fmaxf(cnt - 1.f, 1.f)) * 0.01f;
  }
}

extern "C" void kernel_launch(void* const* d_in, const int* in_sizes, int n_in,
                              void* d_out, int out_size, void* d_ws, size_t ws_size,
                              hipStream_t stream) {
  const float* logits = (const float*)d_in[0];
  const float* tgt    = (const float*)d_in[1];
  const unsigned char* mask = (const unsigned char*)d_in[2];
  float* out = (float*)d_out;
  float* ws  = (float*)d_ws;

  row_stats_kernel<<<dim3(4096), dim3(256), 0, stream>>>(logits, tgt, mask, ws);
  pair_kernel<<<dim3(NBP), dim3(128), 0, stream>>>(mask, ws);
  final_combine_kernel<<<dim3(1), dim3(128), 0, stream>>>(ws, out);
}